// Round 17
// baseline (160.964 us; speedup 1.0000x reference)
//
#include <hip/hip_runtime.h>
#include <hip/hip_fp16.h>
#include <math.h>

#define N_NODES 50000
#define N_EDGES 800000
#define E_TOT   (N_EDGES + N_NODES)   // 850000, self-loops appended
#define NEG_SLOPE 0.2f
#define NSLICE 8
#define NODES_PER_SLICE (N_NODES / NSLICE)   // 6250
#define SLICE_BLOCKS 256                     // blocks per slice -> grid 2048

// ---- workspace layout (bytes), 16-aligned ----
#define CNT_OFF    0UL           // N u32 (zeroed by node_alpha1 each call)
#define CSR_OFF    200000UL      // N*64 u16 = 6,400,000 -> 6,600,000
#define VAS2_OFF   6600000UL     // 256 f32 -> 6,601,024
#define VAD2_OFF   6601024UL     // 256 f32 -> 6,602,048
#define PK1_OFF    6602048UL     // N*8 f32 packed {as1[4], x[3], pad} -> 8,202,048
#define AD1_OFF    8202048UL     // N*4 f32 -> 9,002,048
#define H2_OFF     9002048UL     // N*64 f16 = 6,400,000 -> 15,402,048
#define AS2_OFF    15402048UL    // N f32 -> 15,602,048
#define AD2_OFF    15602048UL    // N f32 -> 15,802,048

__device__ __forceinline__ float wave_reduce_sum(float v) {
    #pragma unroll
    for (int off = 32; off > 0; off >>= 1) v += __shfl_xor(v, off, 64);
    return v;
}
// reductions within an 8-lane group (xor<8 stays inside the group)
__device__ __forceinline__ float grp8_reduce_sum(float v) {
    #pragma unroll
    for (int off = 4; off > 0; off >>= 1) v += __shfl_xor(v, off, 64);
    return v;
}
__device__ __forceinline__ float lrelu(float v) { return v > 0.f ? v : NEG_SLOPE * v; }
__device__ __forceinline__ float elu(float v)   { return v > 0.f ? v : __expf(v) - 1.f; }

// K1: per-node layer-1 alphas + packed gather record + cnt zero + weight folds.
__global__ void node_alpha1(const float* __restrict__ x, const float* __restrict__ W1,
                            const float* __restrict__ a_s1, const float* __restrict__ a_d1,
                            const float* __restrict__ W2, const float* __restrict__ a_s2,
                            const float* __restrict__ a_d2,
                            float* __restrict__ pk1, float* __restrict__ ad1,
                            unsigned* __restrict__ cnt,
                            float* __restrict__ vas2, float* __restrict__ vad2) {
    __shared__ float svs[12], svd[12];
    int t = threadIdx.x, h = t >> 6, lane = t & 63;
    float avs = a_s1[h*64 + lane], avd = a_d1[h*64 + lane];
    #pragma unroll
    for (int k = 0; k < 3; ++k) {
        float w = W1[k*256 + h*64 + lane];
        float ps = wave_reduce_sum(w * avs);
        float pd = wave_reduce_sum(w * avd);
        if (lane == 0) { svs[k*4+h] = ps; svd[k*4+h] = pd; }
    }
    if (blockIdx.x < 64) {
        int k = blockIdx.x*4 + h;
        float wv = W2[k*64 + lane];
        float ps2 = wave_reduce_sum(wv * a_s2[lane]);
        float pd2 = wave_reduce_sum(wv * a_d2[lane]);
        if (lane == 0) { vas2[k] = ps2; vad2[k] = pd2; }
    }
    __syncthreads();
    int n = blockIdx.x*256 + t;
    if (n >= N_NODES) return;
    cnt[n] = 0u;
    float x0 = x[n*3+0], x1 = x[n*3+1], x2v = x[n*3+2];
    float4 s, d;
    s.x = x0*svs[0] + x1*svs[4] + x2v*svs[8];
    s.y = x0*svs[1] + x1*svs[5] + x2v*svs[9];
    s.z = x0*svs[2] + x1*svs[6] + x2v*svs[10];
    s.w = x0*svs[3] + x1*svs[7] + x2v*svs[11];
    d.x = x0*svd[0] + x1*svd[4] + x2v*svd[8];
    d.y = x0*svd[1] + x1*svd[5] + x2v*svd[9];
    d.z = x0*svd[2] + x1*svd[6] + x2v*svd[10];
    d.w = x0*svd[3] + x1*svd[7] + x2v*svd[11];
    float4* pp = (float4*)(pk1 + (size_t)n*8);
    pp[0] = s;
    pp[1] = make_float4(x0, x1, x2v, 0.f);
    *(float4*)(ad1 + (size_t)n*4) = d;
}

// K2: build padded u16 CSR, XCD-sliced (round-10 form; best measured).
__global__ void build_csr(const int* __restrict__ ei, unsigned* __restrict__ cnt,
                          unsigned short* __restrict__ csr) {
    int slice = blockIdx.x & (NSLICE-1);
    int bi    = blockIdx.x >> 3;            // 0..SLICE_BLOCKS-1
    int lo = slice * NODES_PER_SLICE, hi = lo + NODES_PER_SLICE;
    const int stride = SLICE_BLOCKS * 256;
    for (int c = bi*256 + threadIdx.x; c < N_EDGES/4; c += stride) {
        int4 d4 = *(const int4*)(ei + N_EDGES + c*4);
        if (d4.x >= lo && d4.x < hi) {
            unsigned p = atomicAdd(&cnt[d4.x], 1u);
            if (p < 64u) csr[((size_t)d4.x << 6) + p] = (unsigned short)ei[c*4+0];
        }
        if (d4.y >= lo && d4.y < hi) {
            unsigned p = atomicAdd(&cnt[d4.y], 1u);
            if (p < 64u) csr[((size_t)d4.y << 6) + p] = (unsigned short)ei[c*4+1];
        }
        if (d4.z >= lo && d4.z < hi) {
            unsigned p = atomicAdd(&cnt[d4.z], 1u);
            if (p < 64u) csr[((size_t)d4.z << 6) + p] = (unsigned short)ei[c*4+2];
        }
        if (d4.w >= lo && d4.w < hi) {
            unsigned p = atomicAdd(&cnt[d4.w], 1u);
            if (p < 64u) csr[((size_t)d4.w << 6) + p] = (unsigned short)ei[c*4+3];
        }
    }
    for (int v = lo + bi*256 + threadIdx.x; v < hi; v += stride) {
        unsigned p = atomicAdd(&cnt[v], 1u);
        if (p < 64u) csr[((size_t)v << 6) + p] = (unsigned short)v;
    }
}

// K3: FUSED layer-1, v3: 32 nodes/block + DOUBLE-BUFFERED phase-B pipeline
// (one barrier per tile, Wt global loads overlap FMA compute) + phase-A
// 1-deep CSR-index prefetch. k0 loop NOT unrolled (round-13 spill lesson).
#define KB 32
__global__ __launch_bounds__(256) void layer1_fused(
        const unsigned short* __restrict__ csr, const unsigned* __restrict__ cnt,
        const float* __restrict__ pk1, const float* __restrict__ ad1,
        const float* __restrict__ W1, const float* __restrict__ b1,
        const float* __restrict__ W2,
        const float* __restrict__ vas2, const float* __restrict__ vad2,
        __half* __restrict__ h2, float* __restrict__ as2, float* __restrict__ ad2) {
    __shared__ float gl[32][13];        // 13 coprime 32 -> conflict-free rows
    __shared__ float xT[2][KB][36];     // double-buffered [k][node]
    __shared__ float Wt[2][KB][64];     // double-buffered [k][c]
    __shared__ float W1s[768], b1s[256];
    __shared__ float pas_part[8][33], pad_part[8][33];
    int t = threadIdx.x;
    W1s[t] = W1[t]; W1s[256+t] = W1[256+t]; W1s[512+t] = W1[512+t];
    b1s[t] = b1[t];
    int n0 = blockIdx.x * 32;
    // ---- phase A: g for 32 nodes, 8 lanes per node, index-prefetched ----
    {
        int subl = t & 7, ng = t >> 3;     // node = n0+ng
        int n = n0 + ng;
        float d0=0.f, d1=0.f, d2=0.f, d3=0.f;
        float g00=0,g01=0,g02=0, g10=0,g11=0,g12=0, g20=0,g21=0,g22=0, g30=0,g31=0,g32=0;
        if (n < N_NODES) {
            unsigned deg = min(cnt[n], 64u);
            const unsigned short* row = csr + ((size_t)n << 6);
            float4 adv = *(const float4*)(ad1 + (size_t)n*4);
            unsigned c = subl;
            int s_cur = (c < deg) ? (int)row[c] : 0;
            while (c < deg) {
                unsigned cn = c + 8;
                int s_nxt = (cn < deg) ? (int)row[cn] : 0;   // prefetch next index
                const float4* pp = (const float4*)(pk1 + (size_t)s_cur*8);
                float4 as = pp[0];
                float4 xv = pp[1];
                float e0 = __expf(lrelu(as.x+adv.x));
                float e1 = __expf(lrelu(as.y+adv.y));
                float e2 = __expf(lrelu(as.z+adv.z));
                float e3 = __expf(lrelu(as.w+adv.w));
                d0 += e0; d1 += e1; d2 += e2; d3 += e3;
                g00 = fmaf(e0,xv.x,g00); g01 = fmaf(e0,xv.y,g01); g02 = fmaf(e0,xv.z,g02);
                g10 = fmaf(e1,xv.x,g10); g11 = fmaf(e1,xv.y,g11); g12 = fmaf(e1,xv.z,g12);
                g20 = fmaf(e2,xv.x,g20); g21 = fmaf(e2,xv.y,g21); g22 = fmaf(e2,xv.z,g22);
                g30 = fmaf(e3,xv.x,g30); g31 = fmaf(e3,xv.y,g31); g32 = fmaf(e3,xv.z,g32);
                c = cn; s_cur = s_nxt;
            }
        }
        float r_0 = 1.f/(grp8_reduce_sum(d0) + 1e-16f);
        float r_1 = 1.f/(grp8_reduce_sum(d1) + 1e-16f);
        float r_2 = 1.f/(grp8_reduce_sum(d2) + 1e-16f);
        float r_3 = 1.f/(grp8_reduce_sum(d3) + 1e-16f);
        g00 = grp8_reduce_sum(g00)*r_0; g01 = grp8_reduce_sum(g01)*r_0; g02 = grp8_reduce_sum(g02)*r_0;
        g10 = grp8_reduce_sum(g10)*r_1; g11 = grp8_reduce_sum(g11)*r_1; g12 = grp8_reduce_sum(g12)*r_1;
        g20 = grp8_reduce_sum(g20)*r_2; g21 = grp8_reduce_sum(g21)*r_2; g22 = grp8_reduce_sum(g22)*r_2;
        g30 = grp8_reduce_sum(g30)*r_3; g31 = grp8_reduce_sum(g31)*r_3; g32 = grp8_reduce_sum(g32)*r_3;
        int subl0 = t & 7, ng0 = t >> 3;
        if (subl0 == 0) {
            gl[ng0][0]=g00;  gl[ng0][1]=g01;  gl[ng0][2]=g02;
            gl[ng0][3]=g10;  gl[ng0][4]=g11;  gl[ng0][5]=g12;
            gl[ng0][6]=g20;  gl[ng0][7]=g21;  gl[ng0][8]=g22;
            gl[ng0][9]=g30;  gl[ng0][10]=g31; gl[ng0][11]=g32;
        }
    }
    __syncthreads();
    // ---- phase B: pipelined GEMM, 32 nodes x 64 ch, 8 outputs/thread ----
    int i = t & 7, j = t >> 3;          // nodes 4i..4i+3, channels 2j,2j+1
    int snode = t & 31, kw = t >> 5;    // staging: node, k-quad group
    float acc[4][2] = {{0,0},{0,0},{0,0},{0,0}};
    float pas = 0.f, pad = 0.f;

    auto stageXT = [&](int buf, int k0) {
        int h = k0 >> 6;                 // runtime head index (register select)
        float gv0 = gl[snode][h*3+0];
        float gv1 = gl[snode][h*3+1];
        float gv2 = gl[snode][h*3+2];
        #pragma unroll
        for (int q = 0; q < 4; ++q) {
            int k  = kw*4 + q;
            int jj = k0 + k;
            float val = gv0*W1s[jj] + gv1*W1s[256+jj] + gv2*W1s[512+jj] + b1s[jj];
            val = elu(val);
            xT[buf][k][snode] = val;
            pas = fmaf(val, vas2[jj], pas);
            pad = fmaf(val, vad2[jj], pad);
        }
    };
    auto stageWT = [&](int buf, int k0) {
        int p = t;
        #pragma unroll
        for (int rr = 0; rr < 2; ++rr, p += 256) {
            int kr = p >> 4, c4 = p & 15;
            *(float4*)(&Wt[buf][kr][c4*4]) = *(const float4*)(W2 + (size_t)(k0+kr)*64 + c4*4);
        }
    };

    stageWT(0, 0);
    stageXT(0, 0);
    __syncthreads();
    for (int tile = 0; tile < 8; ++tile) {   // NOT unrolled
        int cur = tile & 1;
        if (tile < 7) {                      // issue next tile's staging FIRST
            stageWT(cur ^ 1, (tile+1)*KB);   // global loads hide under FMAs below
            stageXT(cur ^ 1, (tile+1)*KB);
        }
        #pragma unroll
        for (int k = 0; k < KB; ++k) {
            float4 xv = *(const float4*)(&xT[cur][k][4*i]);
            float2 wv = *(const float2*)(&Wt[cur][k][2*j]);
            acc[0][0]=fmaf(xv.x,wv.x,acc[0][0]); acc[0][1]=fmaf(xv.x,wv.y,acc[0][1]);
            acc[1][0]=fmaf(xv.y,wv.x,acc[1][0]); acc[1][1]=fmaf(xv.y,wv.y,acc[1][1]);
            acc[2][0]=fmaf(xv.z,wv.x,acc[2][0]); acc[2][1]=fmaf(xv.z,wv.y,acc[2][1]);
            acc[3][0]=fmaf(xv.w,wv.x,acc[3][0]); acc[3][1]=fmaf(xv.w,wv.y,acc[3][1]);
        }
        __syncthreads();                     // one barrier per tile
    }
    // pas/pad: cross-wave reduce (8 kw partials per node)
    pas_part[kw][snode] = pas;
    pad_part[kw][snode] = pad;
    __syncthreads();
    if (t < 32) {
        int n = n0 + t;
        if (n < N_NODES) {
            float s = 0.f, d = 0.f;
            #pragma unroll
            for (int m = 0; m < 8; ++m) { s += pas_part[m][t]; d += pad_part[m][t]; }
            as2[n] = s; ad2[n] = d;
        }
    }
    #pragma unroll
    for (int ii = 0; ii < 4; ++ii) {
        int n = n0 + 4*i + ii;
        if (n < N_NODES)
            *(__half2*)(h2 + (size_t)n*64 + 2*j) = __floats2half2_rn(acc[ii][0], acc[ii][1]);
    }
}

// K4: fused layer-2 + FC + sigmoid. One wave per node.
// Alpha: lane = edge (loop-free). Aggregation: lane = channel, 8-deep unrolled
// edge loop, s/ex broadcast via shfl -> 8 independent h2 loads in flight.
__global__ void gat2_node(const unsigned short* __restrict__ csr, const unsigned* __restrict__ cnt,
                          const __half* __restrict__ h2, const float* __restrict__ as2,
                          const float* __restrict__ ad2, const float* __restrict__ b2,
                          const float* __restrict__ Wfc, const float* __restrict__ bfc,
                          float* __restrict__ out) {
    int lane = threadIdx.x & 63, w = threadIdx.x >> 6;
    int n = blockIdx.x*4 + w;               // grid exact: 12500*4 = 50000
    unsigned deg = min(cnt[n], 64u);        // >=1 (self-loop)
    const unsigned short* row = csr + ((size_t)n << 6);
    float adv = ad2[n];
    int s_l = 0; float ex_l = 0.f;
    if (lane < (int)deg) {
        s_l = row[lane];
        ex_l = __expf(lrelu(as2[s_l] + adv));
    }
    float den = wave_reduce_sum(ex_l);
    float acc = 0.f;
    unsigned degr = (deg + 7u) & ~7u;       // wave-uniform trip count
    for (unsigned c = 0; c < degr; c += 8) {
        #pragma unroll
        for (int u = 0; u < 8; ++u) {
            int e = (int)c + u;
            float ex = __shfl(ex_l, e, 64);
            int   s  = __shfl(s_l,  e, 64);
            float hv = __half2float(h2[((size_t)s << 6) + lane]);
            acc = fmaf(hv, ex, acc);
        }
    }
    float v = elu(acc/(den + 1e-16f) + b2[lane]);
    float part = wave_reduce_sum(v * Wfc[lane]);
    if (lane == 0) out[n] = 1.f/(1.f + __expf(-(part + bfc[0])));
}

extern "C" void kernel_launch(void* const* d_in, const int* in_sizes, int n_in,
                              void* d_out, int out_size, void* d_ws, size_t ws_size,
                              hipStream_t stream) {
    const float* x      = (const float*)d_in[0];
    const int*   ei     = (const int*)  d_in[1];
    const float* W1     = (const float*)d_in[2];
    const float* a_src1 = (const float*)d_in[3];
    const float* a_dst1 = (const float*)d_in[4];
    const float* b1     = (const float*)d_in[5];
    const float* W2     = (const float*)d_in[6];
    const float* a_src2 = (const float*)d_in[7];
    const float* a_dst2 = (const float*)d_in[8];
    const float* b2     = (const float*)d_in[9];
    const float* Wfc    = (const float*)d_in[10];
    const float* bfc    = (const float*)d_in[11];
    float* out = (float*)d_out;

    char* ws = (char*)d_ws;
    unsigned*       cnt  = (unsigned*)      (ws + CNT_OFF);
    unsigned short* csr  = (unsigned short*)(ws + CSR_OFF);
    float*          vas2 = (float*)         (ws + VAS2_OFF);
    float*          vad2 = (float*)         (ws + VAD2_OFF);
    float*          pk1  = (float*)         (ws + PK1_OFF);
    float*          ad1  = (float*)         (ws + AD1_OFF);
    __half*         h2   = (__half*)        (ws + H2_OFF);
    float*          as2  = (float*)         (ws + AS2_OFF);
    float*          ad2  = (float*)         (ws + AD2_OFF);

    const int BLK = 256;
    node_alpha1  <<<(N_NODES + BLK - 1)/BLK, BLK, 0, stream>>>(
        x, W1, a_src1, a_dst1, W2, a_src2, a_dst2, pk1, ad1, cnt, vas2, vad2);
    build_csr    <<<NSLICE*SLICE_BLOCKS, BLK, 0, stream>>>(ei, cnt, csr);
    layer1_fused <<<(N_NODES + 31)/32, BLK, 0, stream>>>(
        csr, cnt, pk1, ad1, W1, b1, W2, vas2, vad2, h2, as2, ad2);
    gat2_node    <<<N_NODES/4, BLK, 0, stream>>>(csr, cnt, h2, as2, ad2, b2, Wfc, bfc, out);
}

// Round 18
// 126.875 us; speedup vs baseline: 1.2687x; 1.2687x over previous
//
#include <hip/hip_runtime.h>
#include <hip/hip_fp16.h>
#include <math.h>

#define N_NODES 50000
#define N_EDGES 800000
#define E_TOT   (N_EDGES + N_NODES)   // 850000, self-loops appended
#define NEG_SLOPE 0.2f
#define NSLICE 8
#define NODES_PER_SLICE (N_NODES / NSLICE)   // 6250
#define SLICE_BLOCKS 256                     // blocks per slice -> grid 2048

// ---- workspace layout (bytes), 16-aligned ----
#define CNT_OFF    0UL           // N u32 (zeroed by node_alpha1 each call)
#define CSR_OFF    200000UL      // N*64 u16 = 6,400,000 -> 6,600,000
#define VAS2_OFF   6600000UL     // 256 f32 -> 6,601,024
#define VAD2_OFF   6601024UL     // 256 f32 -> 6,602,048
#define PK1_OFF    6602048UL     // N*8 f32 packed {as1[4], x[3], pad} -> 8,202,048
#define AD1_OFF    8202048UL     // N*4 f32 -> 9,002,048
#define H2_OFF     9002048UL     // N*64 f16 = 6,400,000 -> 15,402,048
#define AS2_OFF    15402048UL    // N f32 -> 15,602,048
#define AD2_OFF    15602048UL    // N f32 -> 15,802,048

__device__ __forceinline__ float wave_reduce_sum(float v) {
    #pragma unroll
    for (int off = 32; off > 0; off >>= 1) v += __shfl_xor(v, off, 64);
    return v;
}
// reductions within an 8-lane group (xor<8 stays inside the group)
__device__ __forceinline__ float grp8_reduce_sum(float v) {
    #pragma unroll
    for (int off = 4; off > 0; off >>= 1) v += __shfl_xor(v, off, 64);
    return v;
}
__device__ __forceinline__ float lrelu(float v) { return v > 0.f ? v : NEG_SLOPE * v; }
__device__ __forceinline__ float elu(float v)   { return v > 0.f ? v : __expf(v) - 1.f; }

// K1: per-node layer-1 alphas + packed gather record + cnt zero + weight folds.
__global__ void node_alpha1(const float* __restrict__ x, const float* __restrict__ W1,
                            const float* __restrict__ a_s1, const float* __restrict__ a_d1,
                            const float* __restrict__ W2, const float* __restrict__ a_s2,
                            const float* __restrict__ a_d2,
                            float* __restrict__ pk1, float* __restrict__ ad1,
                            unsigned* __restrict__ cnt,
                            float* __restrict__ vas2, float* __restrict__ vad2) {
    __shared__ float svs[12], svd[12];
    int t = threadIdx.x, h = t >> 6, lane = t & 63;
    float avs = a_s1[h*64 + lane], avd = a_d1[h*64 + lane];
    #pragma unroll
    for (int k = 0; k < 3; ++k) {
        float w = W1[k*256 + h*64 + lane];
        float ps = wave_reduce_sum(w * avs);
        float pd = wave_reduce_sum(w * avd);
        if (lane == 0) { svs[k*4+h] = ps; svd[k*4+h] = pd; }
    }
    if (blockIdx.x < 64) {
        int k = blockIdx.x*4 + h;
        float wv = W2[k*64 + lane];
        float ps2 = wave_reduce_sum(wv * a_s2[lane]);
        float pd2 = wave_reduce_sum(wv * a_d2[lane]);
        if (lane == 0) { vas2[k] = ps2; vad2[k] = pd2; }
    }
    __syncthreads();
    int n = blockIdx.x*256 + t;
    if (n >= N_NODES) return;
    cnt[n] = 0u;
    float x0 = x[n*3+0], x1 = x[n*3+1], x2v = x[n*3+2];
    float4 s, d;
    s.x = x0*svs[0] + x1*svs[4] + x2v*svs[8];
    s.y = x0*svs[1] + x1*svs[5] + x2v*svs[9];
    s.z = x0*svs[2] + x1*svs[6] + x2v*svs[10];
    s.w = x0*svs[3] + x1*svs[7] + x2v*svs[11];
    d.x = x0*svd[0] + x1*svd[4] + x2v*svd[8];
    d.y = x0*svd[1] + x1*svd[5] + x2v*svd[9];
    d.z = x0*svd[2] + x1*svd[6] + x2v*svd[10];
    d.w = x0*svd[3] + x1*svd[7] + x2v*svd[11];
    float4* pp = (float4*)(pk1 + (size_t)n*8);
    pp[0] = s;
    pp[1] = make_float4(x0, x1, x2v, 0.f);
    *(float4*)(ad1 + (size_t)n*4) = d;
}

// K2: build padded u16 CSR, XCD-sliced (round-10 form; best measured).
__global__ void build_csr(const int* __restrict__ ei, unsigned* __restrict__ cnt,
                          unsigned short* __restrict__ csr) {
    int slice = blockIdx.x & (NSLICE-1);
    int bi    = blockIdx.x >> 3;            // 0..SLICE_BLOCKS-1
    int lo = slice * NODES_PER_SLICE, hi = lo + NODES_PER_SLICE;
    const int stride = SLICE_BLOCKS * 256;
    for (int c = bi*256 + threadIdx.x; c < N_EDGES/4; c += stride) {
        int4 d4 = *(const int4*)(ei + N_EDGES + c*4);
        if (d4.x >= lo && d4.x < hi) {
            unsigned p = atomicAdd(&cnt[d4.x], 1u);
            if (p < 64u) csr[((size_t)d4.x << 6) + p] = (unsigned short)ei[c*4+0];
        }
        if (d4.y >= lo && d4.y < hi) {
            unsigned p = atomicAdd(&cnt[d4.y], 1u);
            if (p < 64u) csr[((size_t)d4.y << 6) + p] = (unsigned short)ei[c*4+1];
        }
        if (d4.z >= lo && d4.z < hi) {
            unsigned p = atomicAdd(&cnt[d4.z], 1u);
            if (p < 64u) csr[((size_t)d4.z << 6) + p] = (unsigned short)ei[c*4+2];
        }
        if (d4.w >= lo && d4.w < hi) {
            unsigned p = atomicAdd(&cnt[d4.w], 1u);
            if (p < 64u) csr[((size_t)d4.w << 6) + p] = (unsigned short)ei[c*4+3];
        }
    }
    for (int v = lo + bi*256 + threadIdx.x; v < hi; v += stride) {
        unsigned p = atomicAdd(&cnt[v], 1u);
        if (p < 64u) csr[((size_t)v << 6) + p] = (unsigned short)v;
    }
}

// K3: FUSED layer-1, v2 (round-16 best) + phase-A index prefetch ONLY.
// 32 nodes/block, conflict-free LDS (xT rows 36, gl rows 13), single-buffered
// phase B (2 barriers/tile -- R17's dbuf regressed: 132 VGPR, 9% occ).
#define KB 32
__global__ __launch_bounds__(256) void layer1_fused(
        const unsigned short* __restrict__ csr, const unsigned* __restrict__ cnt,
        const float* __restrict__ pk1, const float* __restrict__ ad1,
        const float* __restrict__ W1, const float* __restrict__ b1,
        const float* __restrict__ W2,
        const float* __restrict__ vas2, const float* __restrict__ vad2,
        __half* __restrict__ h2, float* __restrict__ as2, float* __restrict__ ad2) {
    __shared__ float gl[32][13];        // 13 coprime 32 -> conflict-free rows
    __shared__ float xT[KB][36];        // [k][node]; write 2-way max, read covers all banks
    __shared__ float Wt[KB][64];        // [k][c]
    __shared__ float W1s[768], b1s[256];
    __shared__ float pas_part[8][33], pad_part[8][33];
    int t = threadIdx.x;
    W1s[t] = W1[t]; W1s[256+t] = W1[256+t]; W1s[512+t] = W1[512+t];
    b1s[t] = b1[t];
    int n0 = blockIdx.x * 32;
    // ---- phase A: g for 32 nodes, 8 lanes/node, 1-deep index prefetch ----
    {
        int subl = t & 7, ng = t >> 3;     // node = n0+ng
        int n = n0 + ng;
        float d0=0.f, d1=0.f, d2=0.f, d3=0.f;
        float g00=0,g01=0,g02=0, g10=0,g11=0,g12=0, g20=0,g21=0,g22=0, g30=0,g31=0,g32=0;
        if (n < N_NODES) {
            unsigned deg = min(cnt[n], 64u);
            const unsigned short* row = csr + ((size_t)n << 6);
            float4 adv = *(const float4*)(ad1 + (size_t)n*4);
            unsigned c = subl;
            int s_cur = (c < deg) ? (int)row[c] : 0;
            while (c < deg) {
                unsigned cn = c + 8;
                int s_nxt = (cn < deg) ? (int)row[cn] : 0;   // prefetch next index
                const float4* pp = (const float4*)(pk1 + (size_t)s_cur*8);
                float4 as = pp[0];
                float4 xv = pp[1];
                float e0 = __expf(lrelu(as.x+adv.x));
                float e1 = __expf(lrelu(as.y+adv.y));
                float e2 = __expf(lrelu(as.z+adv.z));
                float e3 = __expf(lrelu(as.w+adv.w));
                d0 += e0; d1 += e1; d2 += e2; d3 += e3;
                g00 = fmaf(e0,xv.x,g00); g01 = fmaf(e0,xv.y,g01); g02 = fmaf(e0,xv.z,g02);
                g10 = fmaf(e1,xv.x,g10); g11 = fmaf(e1,xv.y,g11); g12 = fmaf(e1,xv.z,g12);
                g20 = fmaf(e2,xv.x,g20); g21 = fmaf(e2,xv.y,g21); g22 = fmaf(e2,xv.z,g22);
                g30 = fmaf(e3,xv.x,g30); g31 = fmaf(e3,xv.y,g31); g32 = fmaf(e3,xv.z,g32);
                c = cn; s_cur = s_nxt;
            }
        }
        float r_0 = 1.f/(grp8_reduce_sum(d0) + 1e-16f);
        float r_1 = 1.f/(grp8_reduce_sum(d1) + 1e-16f);
        float r_2 = 1.f/(grp8_reduce_sum(d2) + 1e-16f);
        float r_3 = 1.f/(grp8_reduce_sum(d3) + 1e-16f);
        g00 = grp8_reduce_sum(g00)*r_0; g01 = grp8_reduce_sum(g01)*r_0; g02 = grp8_reduce_sum(g02)*r_0;
        g10 = grp8_reduce_sum(g10)*r_1; g11 = grp8_reduce_sum(g11)*r_1; g12 = grp8_reduce_sum(g12)*r_1;
        g20 = grp8_reduce_sum(g20)*r_2; g21 = grp8_reduce_sum(g21)*r_2; g22 = grp8_reduce_sum(g22)*r_2;
        g30 = grp8_reduce_sum(g30)*r_3; g31 = grp8_reduce_sum(g31)*r_3; g32 = grp8_reduce_sum(g32)*r_3;
        if (subl == 0) {
            gl[ng][0]=g00;  gl[ng][1]=g01;  gl[ng][2]=g02;
            gl[ng][3]=g10;  gl[ng][4]=g11;  gl[ng][5]=g12;
            gl[ng][6]=g20;  gl[ng][7]=g21;  gl[ng][8]=g22;
            gl[ng][9]=g30;  gl[ng][10]=g31; gl[ng][11]=g32;
        }
    }
    __syncthreads();
    // ---- phase B: GEMM, 32 nodes x 64 ch, 8 outputs/thread (single-buffered) ----
    int i = t & 7, j = t >> 3;          // nodes 4i..4i+3, channels 2j,2j+1
    int snode = t & 31, kw = t >> 5;    // staging: node, k-quad group
    float acc[4][2] = {{0,0},{0,0},{0,0},{0,0}};
    float pas = 0.f, pad = 0.f;
    for (int k0 = 0; k0 < 256; k0 += KB) {   // NOT unrolled
        __syncthreads();                     // previous tile consumed
        {
            int h = k0 >> 6;                 // runtime head index
            float gv0 = gl[snode][h*3+0];
            float gv1 = gl[snode][h*3+1];
            float gv2 = gl[snode][h*3+2];
            #pragma unroll
            for (int q = 0; q < 4; ++q) {
                int k  = kw*4 + q;
                int jj = k0 + k;
                float val = gv0*W1s[jj] + gv1*W1s[256+jj] + gv2*W1s[512+jj] + b1s[jj];
                val = elu(val);
                xT[k][snode] = val;
                pas = fmaf(val, vas2[jj], pas);
                pad = fmaf(val, vad2[jj], pad);
            }
        }
        int p = t;
        #pragma unroll
        for (int rr = 0; rr < 2; ++rr, p += 256) {
            int kr = p >> 4, c4 = p & 15;
            *(float4*)(&Wt[kr][c4*4]) = *(const float4*)(W2 + (size_t)(k0+kr)*64 + c4*4);
        }
        __syncthreads();
        #pragma unroll
        for (int k = 0; k < KB; ++k) {
            float4 xv = *(const float4*)(&xT[k][4*i]);
            float2 wv = *(const float2*)(&Wt[k][2*j]);
            acc[0][0]=fmaf(xv.x,wv.x,acc[0][0]); acc[0][1]=fmaf(xv.x,wv.y,acc[0][1]);
            acc[1][0]=fmaf(xv.y,wv.x,acc[1][0]); acc[1][1]=fmaf(xv.y,wv.y,acc[1][1]);
            acc[2][0]=fmaf(xv.z,wv.x,acc[2][0]); acc[2][1]=fmaf(xv.z,wv.y,acc[2][1]);
            acc[3][0]=fmaf(xv.w,wv.x,acc[3][0]); acc[3][1]=fmaf(xv.w,wv.y,acc[3][1]);
        }
    }
    // pas/pad: cross-wave reduce (8 kw partials per node)
    pas_part[kw][snode] = pas;
    pad_part[kw][snode] = pad;
    __syncthreads();
    if (t < 32) {
        int n = n0 + t;
        if (n < N_NODES) {
            float s = 0.f, d = 0.f;
            #pragma unroll
            for (int m = 0; m < 8; ++m) { s += pas_part[m][t]; d += pad_part[m][t]; }
            as2[n] = s; ad2[n] = d;
        }
    }
    #pragma unroll
    for (int ii = 0; ii < 4; ++ii) {
        int n = n0 + 4*i + ii;
        if (n < N_NODES)
            *(__half2*)(h2 + (size_t)n*64 + 2*j) = __floats2half2_rn(acc[ii][0], acc[ii][1]);
    }
}

// K4: fused layer-2 + FC + sigmoid. One wave per node.
// Alpha: lane = edge (loop-free). Aggregation: lane = channel, 8-deep unrolled
// edge loop, s/ex broadcast via shfl -> 8 independent h2 loads in flight.
__global__ void gat2_node(const unsigned short* __restrict__ csr, const unsigned* __restrict__ cnt,
                          const __half* __restrict__ h2, const float* __restrict__ as2,
                          const float* __restrict__ ad2, const float* __restrict__ b2,
                          const float* __restrict__ Wfc, const float* __restrict__ bfc,
                          float* __restrict__ out) {
    int lane = threadIdx.x & 63, w = threadIdx.x >> 6;
    int n = blockIdx.x*4 + w;               // grid exact: 12500*4 = 50000
    unsigned deg = min(cnt[n], 64u);        // >=1 (self-loop)
    const unsigned short* row = csr + ((size_t)n << 6);
    float adv = ad2[n];
    int s_l = 0; float ex_l = 0.f;
    if (lane < (int)deg) {
        s_l = row[lane];
        ex_l = __expf(lrelu(as2[s_l] + adv));
    }
    float den = wave_reduce_sum(ex_l);
    float acc = 0.f;
    unsigned degr = (deg + 7u) & ~7u;       // wave-uniform trip count
    for (unsigned c = 0; c < degr; c += 8) {
        #pragma unroll
        for (int u = 0; u < 8; ++u) {
            int e = (int)c + u;
            float ex = __shfl(ex_l, e, 64);
            int   s  = __shfl(s_l,  e, 64);
            float hv = __half2float(h2[((size_t)s << 6) + lane]);
            acc = fmaf(hv, ex, acc);
        }
    }
    float v = elu(acc/(den + 1e-16f) + b2[lane]);
    float part = wave_reduce_sum(v * Wfc[lane]);
    if (lane == 0) out[n] = 1.f/(1.f + __expf(-(part + bfc[0])));
}

extern "C" void kernel_launch(void* const* d_in, const int* in_sizes, int n_in,
                              void* d_out, int out_size, void* d_ws, size_t ws_size,
                              hipStream_t stream) {
    const float* x      = (const float*)d_in[0];
    const int*   ei     = (const int*)  d_in[1];
    const float* W1     = (const float*)d_in[2];
    const float* a_src1 = (const float*)d_in[3];
    const float* a_dst1 = (const float*)d_in[4];
    const float* b1     = (const float*)d_in[5];
    const float* W2     = (const float*)d_in[6];
    const float* a_src2 = (const float*)d_in[7];
    const float* a_dst2 = (const float*)d_in[8];
    const float* b2     = (const float*)d_in[9];
    const float* Wfc    = (const float*)d_in[10];
    const float* bfc    = (const float*)d_in[11];
    float* out = (float*)d_out;

    char* ws = (char*)d_ws;
    unsigned*       cnt  = (unsigned*)      (ws + CNT_OFF);
    unsigned short* csr  = (unsigned short*)(ws + CSR_OFF);
    float*          vas2 = (float*)         (ws + VAS2_OFF);
    float*          vad2 = (float*)         (ws + VAD2_OFF);
    float*          pk1  = (float*)         (ws + PK1_OFF);
    float*          ad1  = (float*)         (ws + AD1_OFF);
    __half*         h2   = (__half*)        (ws + H2_OFF);
    float*          as2  = (float*)         (ws + AS2_OFF);
    float*          ad2  = (float*)         (ws + AD2_OFF);

    const int BLK = 256;
    node_alpha1  <<<(N_NODES + BLK - 1)/BLK, BLK, 0, stream>>>(
        x, W1, a_src1, a_dst1, W2, a_src2, a_dst2, pk1, ad1, cnt, vas2, vad2);
    build_csr    <<<NSLICE*SLICE_BLOCKS, BLK, 0, stream>>>(ei, cnt, csr);
    layer1_fused <<<(N_NODES + 31)/32, BLK, 0, stream>>>(
        csr, cnt, pk1, ad1, W1, b1, W2, vas2, vad2, h2, as2, ad2);
    gat2_node    <<<N_NODES/4, BLK, 0, stream>>>(csr, cnt, h2, as2, ad2, b2, Wfc, bfc, out);
}